// Round 1
// 103.737 us; speedup vs baseline: 1.0283x; 1.0283x over previous
//
#include <hip/hip_runtime.h>
#include <hip/hip_bf16.h>
#include <math.h>

// GAT layer, V=8192, E=262144, D=128.
// out[i] = (S + sum_{distinct (i,j)} (exp(a_ij)-1)*hw[j]) / (V + sum (exp(a_ij)-1))
// a_ij = leakyrelu(s1[i]+s2[j], 0.2); s1/s2 = hw @ att halves; S = colsum(hw).
//
// R13 -> R14:
//  (1) k_row: per-entry ballot dedup replaced by a wave-private 8192-bit LDS
//      bitmap pre-pass (atomicOr claim; losers zero their packed w in place).
//      Duplicate edges carry bit-identical w, so any single survivor is exact.
//      Main gather loop is now ballot-free (pure shift/load/FMA).
//  (2) k_hw: W staging rewritten as scalar-coalesced read + 8-way store
//      (was 16-way conflicted), colsum scratch stored as float4 b128
//      (was 4x 4-way-conflicted scalars). Predict SQ_LDS_BANK_CONFLICT
//      1.97M -> <0.7M on k_hw.
// Structure otherwise identical to the verified R9/105.8us configuration.

#define V 8192
#define E 262144
#define D 128
#define NEG_SLOPE 0.2f
#define CAP 96     // bucket capacity/row; max expected degree ~55 (11-sigma safe)
#define CSTRIDE 16 // cnt padded: one counter per 64B cache line

#define FMA4(acc, hv, wv) { acc.x += (hv)*(wv).x; acc.y += (hv)*(wv).y; \
                            acc.z += (hv)*(wv).z; acc.w += (hv)*(wv).w; }

__device__ __forceinline__ unsigned short f2bf(float f) {   // RNE fp32->bf16
    unsigned u = __float_as_uint(f);
    return (unsigned short)((u + 0x7fffu + ((u >> 16) & 1u)) >> 16);
}
__device__ __forceinline__ float bf2f_low(int p) {          // low 16 bits -> float
    return __uint_as_float(((unsigned)p) << 16);
}

// ---------------- K1: hw(bf16) = h @ W^T, fused s1/s2 + colsum partials ------
// 256 blocks x 256 thr, 32 rows/block, 4 rows/thread.
__global__ __launch_bounds__(256) void k_hw(const float* __restrict__ h,
                                            const float* __restrict__ W,
                                            const float* __restrict__ att,
                                            unsigned short* __restrict__ hwb,
                                            float* __restrict__ s1,
                                            float* __restrict__ s2,
                                            float* __restrict__ Pb,
                                            int* __restrict__ cnt) {
    __shared__ float Wt[D * 132];      // W transposed, pad 132
    __shared__ float atts[2 * D];
    __shared__ float scr[8 * D];       // colsum scratch
    int t = threadIdx.x, b = blockIdx.x;
    int g = b * 256 + t;               // zero padded cnt (2 ints/thread)
    cnt[g] = 0;
    cnt[g + V * CSTRIDE / 2] = 0;
    atts[t] = att[t];
    // scalar-coalesced staging: lane-fast k, write stride 132 floats
    // -> bank stride 4 -> 8 banks/64 lanes (8-way, was 16-way with f4 scheme)
    for (int f = t; f < D * D; f += 256) {
        int o = f >> 7, k = f & 127;
        Wt[k * 132 + o] = W[f];        // W[o][k] -> Wt[k][o]
    }
    __syncthreads();

    int c4 = (t & 31) * 4;   // 4-col group
    int rq = t >> 5;         // 0..7; rows rq, rq+8, rq+16, rq+24
    int r0 = b * 32;
    float4 a0 = make_float4(0.f,0.f,0.f,0.f), a1 = a0, a2 = a0, a3 = a0;
    const float* h0p = &h[(r0 + rq     ) * D];
    const float* h1p = &h[(r0 + rq +  8) * D];
    const float* h2p = &h[(r0 + rq + 16) * D];
    const float* h3p = &h[(r0 + rq + 24) * D];
    #pragma unroll 4
    for (int kq = 0; kq < D; kq += 4) {
        float4 w0 = *(const float4*)&Wt[(kq + 0) * 132 + c4];
        float4 w1 = *(const float4*)&Wt[(kq + 1) * 132 + c4];
        float4 w2 = *(const float4*)&Wt[(kq + 2) * 132 + c4];
        float4 w3 = *(const float4*)&Wt[(kq + 3) * 132 + c4];
        float4 hv;
        hv = *(const float4*)&h0p[kq];   // wave-broadcast 16B
        FMA4(a0, hv.x, w0); FMA4(a0, hv.y, w1); FMA4(a0, hv.z, w2); FMA4(a0, hv.w, w3);
        hv = *(const float4*)&h1p[kq];
        FMA4(a1, hv.x, w0); FMA4(a1, hv.y, w1); FMA4(a1, hv.z, w2); FMA4(a1, hv.w, w3);
        hv = *(const float4*)&h2p[kq];
        FMA4(a2, hv.x, w0); FMA4(a2, hv.y, w1); FMA4(a2, hv.z, w2); FMA4(a2, hv.w, w3);
        hv = *(const float4*)&h3p[kq];
        FMA4(a3, hv.x, w0); FMA4(a3, hv.y, w1); FMA4(a3, hv.z, w2); FMA4(a3, hv.w, w3);
    }
    *(ushort4*)&hwb[(r0 + rq     ) * D + c4] = make_ushort4(f2bf(a0.x), f2bf(a0.y), f2bf(a0.z), f2bf(a0.w));
    *(ushort4*)&hwb[(r0 + rq +  8) * D + c4] = make_ushort4(f2bf(a1.x), f2bf(a1.y), f2bf(a1.z), f2bf(a1.w));
    *(ushort4*)&hwb[(r0 + rq + 16) * D + c4] = make_ushort4(f2bf(a2.x), f2bf(a2.y), f2bf(a2.z), f2bf(a2.w));
    *(ushort4*)&hwb[(r0 + rq + 24) * D + c4] = make_ushort4(f2bf(a3.x), f2bf(a3.y), f2bf(a3.z), f2bf(a3.w));

    // fused s1/s2 (fp32, 32-lane group reduce), 4 rows
    float q1[4], q2[4];
    float4* accs[4] = {&a0, &a1, &a2, &a3};
    #pragma unroll
    for (int r = 0; r < 4; ++r) {
        float4 v = *accs[r];
        q1[r] = v.x * atts[c4] + v.y * atts[c4 + 1] + v.z * atts[c4 + 2] + v.w * atts[c4 + 3];
        q2[r] = v.x * atts[D + c4] + v.y * atts[D + c4 + 1] + v.z * atts[D + c4 + 2] + v.w * atts[D + c4 + 3];
    }
    #pragma unroll
    for (int m = 16; m; m >>= 1) {
        #pragma unroll
        for (int r = 0; r < 4; ++r) {
            q1[r] += __shfl_xor(q1[r], m);
            q2[r] += __shfl_xor(q2[r], m);
        }
    }
    if ((t & 31) == 0) {
        #pragma unroll
        for (int r = 0; r < 4; ++r) {
            s1[r0 + rq + r * 8] = q1[r];
            s2[r0 + rq + r * 8] = q2[r];
        }
    }

    // colsum partial: 4-row sums -> LDS (b128, conflict-free) -> Pb[b][col]
    *(float4*)&scr[rq * D + c4] = make_float4(a0.x + a1.x + a2.x + a3.x,
                                              a0.y + a1.y + a2.y + a3.y,
                                              a0.z + a1.z + a2.z + a3.z,
                                              a0.w + a1.w + a2.w + a3.w);
    __syncthreads();
    if (t < D) {
        float s = 0.f;
        #pragma unroll
        for (int r = 0; r < 8; ++r) s += scr[r * D + t];
        Pb[b * D + t] = s;
    }
}

// ---------------- K2: scatter (b<1024, 1 edge/thr) | S-reduce (b==1024) -----
__global__ __launch_bounds__(256) void k_scatter(const int* __restrict__ ei,
                                                 const float* __restrict__ s1,
                                                 const float* __restrict__ s2,
                                                 int* __restrict__ cnt,
                                                 int* __restrict__ bucket,
                                                 const float* __restrict__ Pb,
                                                 float* __restrict__ S) {
    int b = blockIdx.x, t = threadIdx.x;
    if (b < 1024) {
        int g = b * 256 + t;               // one edge/thread: single atomic
        int src = ei[g];
        int dst = ei[E + g];
        float a = s1[src] + s2[dst];
        a = a > 0.f ? a : NEG_SLOPE * a;
        float w = expf(a) - 1.f;
        int pos = atomicAdd(&cnt[src * CSTRIDE], 1);   // private 64B line per row
        if (pos < CAP)
            bucket[src * CAP + pos] = (dst << 16) | (int)f2bf(w);  // 4B packed
    } else {
        __shared__ float red[256];
        int c = t & 127, half = t >> 7;
        float s = 0.f;
        #pragma unroll 4
        for (int r = half; r < 256; r += 2)
            s += Pb[r * D + c];
        red[t] = s;
        __syncthreads();
        if (t < D) S[t] = red[t] + red[D + t];
    }
}

// ---------------- K3: per-row gather, 8 entries/iter, bitmap-prepass dedup ---
// 2048 blocks x 256 thr, 1 row/wave. LDS-staged bucket, b128 broadcasts.
// Dedup done ONCE up front: wave-private 8192-bit LDS bitmap, atomicOr claim,
// losers zero their packed w in LDS. Main loop is ballot-free.
__global__ __launch_bounds__(256) void k_row(const int* __restrict__ bucket,
                                             const int* __restrict__ cnt,
                                             const unsigned short* __restrict__ hwb,
                                             const float* __restrict__ S,
                                             float* __restrict__ out) {
    __shared__ int lb[4][CAP];             // 1.5KB, 16B-aligned per wave
    __shared__ unsigned bm[4][256];        // 8192-bit dedup bitmap per wave (4KB)
    int t = threadIdx.x;
    int wv = t >> 6, lane = t & 63;
    int row = blockIdx.x * 4 + wv;
    int deg = cnt[row * CSTRIDE];
    if (deg > CAP) deg = CAP;
    // zero wave-private bitmap: 64 lanes x 16B, conflict-free
    *(uint4*)&bm[wv][lane * 4] = make_uint4(0u, 0u, 0u, 0u);
    const int* bk = bucket + row * CAP;
    int e0 = bk[lane];
    int e1 = (lane < CAP - 64) ? bk[64 + lane] : 0;
    int p0 = (lane < deg)      ? e0 : 0;   // dead slots: w=0
    int p1 = (64 + lane < deg) ? e1 : 0;
    // dedup pre-pass: exactly one claimant per dst survives (dup w bit-identical)
    if (lane < deg) {
        unsigned d = (unsigned)p0 >> 16;
        unsigned m = 1u << (d & 31);
        if (atomicOr(&bm[wv][d >> 5], m) & m) p0 &= ~0xFFFF;   // loser: w=0
    }
    if (64 + lane < deg) {
        unsigned d = (unsigned)p1 >> 16;
        unsigned m = 1u << (d & 31);
        if (atomicOr(&bm[wv][d >> 5], m) & m) p1 &= ~0xFFFF;
    }
    lb[wv][lane] = p0;
    if (lane < CAP - 64) lb[wv][64 + lane] = p1;
    int n0 = deg < 64 ? deg : 64;
    float accx = 0.f, accy = 0.f, dex = 0.f;
    const int* myb = lb[wv];
    int col2 = lane * 2;
    int j = 0;
    for (; j + 8 <= n0; j += 8) {
        int4 pa = *(const int4*)&myb[j];        // 2x ds_read_b128 broadcast
        int4 pb = *(const int4*)&myb[j + 4];
        int da0 = pa.x >> 16, da1 = pa.y >> 16, da2 = pa.z >> 16, da3 = pa.w >> 16;
        int db0 = pb.x >> 16, db1 = pb.y >> 16, db2 = pb.z >> 16, db3 = pb.w >> 16;
        unsigned ha0 = *(const unsigned*)&hwb[da0 * D + col2];   // 8 in flight
        unsigned ha1 = *(const unsigned*)&hwb[da1 * D + col2];
        unsigned ha2 = *(const unsigned*)&hwb[da2 * D + col2];
        unsigned ha3 = *(const unsigned*)&hwb[da3 * D + col2];
        unsigned hb0 = *(const unsigned*)&hwb[db0 * D + col2];
        unsigned hb1 = *(const unsigned*)&hwb[db1 * D + col2];
        unsigned hb2 = *(const unsigned*)&hwb[db2 * D + col2];
        unsigned hb3 = *(const unsigned*)&hwb[db3 * D + col2];
        float wa0 = bf2f_low(pa.x);
        float wa1 = bf2f_low(pa.y);
        float wa2 = bf2f_low(pa.z);
        float wa3 = bf2f_low(pa.w);
        float wb0 = bf2f_low(pb.x);
        float wb1 = bf2f_low(pb.y);
        float wb2 = bf2f_low(pb.z);
        float wb3 = bf2f_low(pb.w);
        accx += wa0 * __uint_as_float(ha0 << 16);
        accy += wa0 * __uint_as_float(ha0 & 0xFFFF0000u);
        accx += wa1 * __uint_as_float(ha1 << 16);
        accy += wa1 * __uint_as_float(ha1 & 0xFFFF0000u);
        accx += wa2 * __uint_as_float(ha2 << 16);
        accy += wa2 * __uint_as_float(ha2 & 0xFFFF0000u);
        accx += wa3 * __uint_as_float(ha3 << 16);
        accy += wa3 * __uint_as_float(ha3 & 0xFFFF0000u);
        accx += wb0 * __uint_as_float(hb0 << 16);
        accy += wb0 * __uint_as_float(hb0 & 0xFFFF0000u);
        accx += wb1 * __uint_as_float(hb1 << 16);
        accy += wb1 * __uint_as_float(hb1 & 0xFFFF0000u);
        accx += wb2 * __uint_as_float(hb2 << 16);
        accy += wb2 * __uint_as_float(hb2 & 0xFFFF0000u);
        accx += wb3 * __uint_as_float(hb3 << 16);
        accy += wb3 * __uint_as_float(hb3 & 0xFFFF0000u);
        dex += wa0 + wa1 + wa2 + wa3 + wb0 + wb1 + wb2 + wb3;
    }
    for (; j < n0; ++j) {                   // tail (<8 entries)
        int pj = myb[j];
        int dj = pj >> 16;
        float wj = bf2f_low(pj);
        unsigned hv = *(const unsigned*)&hwb[dj * D + col2];
        accx += wj * __uint_as_float(hv << 16);
        accy += wj * __uint_as_float(hv & 0xFFFF0000u);
        dex += wj;
    }
    for (j = 64; j < deg; ++j) {            // slots 64..95 (rare: deg>64)
        int pj = myb[j];
        int dj = pj >> 16;
        float wj = bf2f_low(pj);
        unsigned hv = *(const unsigned*)&hwb[dj * D + col2];
        accx += wj * __uint_as_float(hv << 16);
        accy += wj * __uint_as_float(hv & 0xFFFF0000u);
        dex += wj;
    }
    float inv = 1.f / ((float)V + dex);
    float2 s = *(const float2*)&S[col2];
    float2 o;
    o.x = (s.x + accx) * inv;
    o.y = (s.y + accy) * inv;
    *(float2*)&out[row * D + col2] = o;
}

extern "C" void kernel_launch(void* const* d_in, const int* in_sizes, int n_in,
                              void* d_out, int out_size, void* d_ws, size_t ws_size,
                              hipStream_t stream) {
    const float* h   = (const float*)d_in[0];
    const int*   ei  = (const int*)d_in[1];
    const float* W   = (const float*)d_in[2];
    const float* att = (const float*)d_in[3];
    float* out = (float*)d_out;

    char* ws = (char*)d_ws;
    // workspace layout (bytes):
    //   hwb    @ 0          2,097,152   (bf16 hw)
    //   s1     @ 2,097,152     32,768
    //   s2     @ 2,129,920     32,768
    //   S      @ 2,162,688        512
    //   cnt    @ 2,163,200    524,288   (V counters padded to 64B lines)
    //   bucket @ 2,687,488  3,145,728   (8192 * 96 * 4B packed)
    //   Pb     @ 5,833,216    131,072   (256 blocks * 128 colsum partials)
    unsigned short* hwb = (unsigned short*)(ws);
    float* s1  = (float*)(ws + 2097152);
    float* s2  = (float*)(ws + 2129920);
    float* S   = (float*)(ws + 2162688);
    int*   cnt = (int*)(ws + 2163200);
    int*   bucket = (int*)(ws + 2687488);
    float* Pb  = (float*)(ws + 5833216);

    k_hw     <<<256,  256, 0, stream>>>(h, W, att, hwb, s1, s2, Pb, cnt);
    k_scatter<<<1025, 256, 0, stream>>>(ei, s1, s2, cnt, bucket, Pb, S);
    k_row    <<<2048, 256, 0, stream>>>(bucket, cnt, hwb, S, out);
}

// Round 2
// 97.072 us; speedup vs baseline: 1.0989x; 1.0687x over previous
//
#include <hip/hip_runtime.h>
#include <hip/hip_bf16.h>
#include <math.h>

// GAT layer, V=8192, E=262144, D=128.
// out[i] = (S + sum_{distinct (i,j)} (exp(a_ij)-1)*hw[j]) / (V + sum (exp(a_ij)-1))
// a_ij = leakyrelu(s1[i]+s2[j], 0.2); s1/s2 = hw @ att halves; S = colsum(hw).
//
// R14 -> R15:
//  (1) k_hw: re-partitioned 256->512 blocks (16 rows/block, 2 rows/thread).
//      Was 1 wave/SIMD (1024 waves / 1024 SIMDs) -> every h-load latency gap
//      exposed. LDS 71KB/block allows 2 blocks/CU -> now 2 waves/SIMD, same
//      arithmetic, half the latency-exposed time. Predict k_hw ~8 -> ~4.5us.
//  (2) S-reduce widened from 1 block to 4 blocks (32 cols each, 8-way row
//      split, coalesced 128B reads) so the Pb reduction (now 512 partials)
//      stays hidden under the 1024 scatter blocks.
// k_row unchanged from the verified R14 (bitmap-prepass dedup, ballot-free).

#define V 8192
#define E 262144
#define D 128
#define NEG_SLOPE 0.2f
#define CAP 96     // bucket capacity/row; max expected degree ~55 (11-sigma safe)
#define CSTRIDE 16 // cnt padded: one counter per 64B cache line
#define HWB 512    // k_hw grid

#define FMA4(acc, hv, wv) { acc.x += (hv)*(wv).x; acc.y += (hv)*(wv).y; \
                            acc.z += (hv)*(wv).z; acc.w += (hv)*(wv).w; }

__device__ __forceinline__ unsigned short f2bf(float f) {   // RNE fp32->bf16
    unsigned u = __float_as_uint(f);
    return (unsigned short)((u + 0x7fffu + ((u >> 16) & 1u)) >> 16);
}
__device__ __forceinline__ float bf2f_low(int p) {          // low 16 bits -> float
    return __uint_as_float(((unsigned)p) << 16);
}

// ---------------- K1: hw(bf16) = h @ W^T, fused s1/s2 + colsum partials ------
// 512 blocks x 256 thr, 16 rows/block, 2 rows/thread, 2 waves/SIMD.
__global__ __launch_bounds__(256) void k_hw(const float* __restrict__ h,
                                            const float* __restrict__ W,
                                            const float* __restrict__ att,
                                            unsigned short* __restrict__ hwb,
                                            float* __restrict__ s1,
                                            float* __restrict__ s2,
                                            float* __restrict__ Pb,
                                            int* __restrict__ cnt) {
    __shared__ float Wt[D * 132];      // W transposed, pad 132
    __shared__ float atts[2 * D];
    __shared__ float scr[8 * D];       // colsum scratch
    int t = threadIdx.x, b = blockIdx.x;
    int g = b * 256 + t;               // 512*256 = 131072 = V*CSTRIDE exactly
    cnt[g] = 0;
    atts[t] = att[t];
    // scalar-coalesced staging: lane-fast k, write stride 132 floats (8-way)
    for (int f = t; f < D * D; f += 256) {
        int o = f >> 7, k = f & 127;
        Wt[k * 132 + o] = W[f];        // W[o][k] -> Wt[k][o]
    }
    __syncthreads();

    int c4 = (t & 31) * 4;   // 4-col group
    int rq = t >> 5;         // 0..7; rows rq, rq+8
    int r0 = b * 16;
    float4 a0 = make_float4(0.f,0.f,0.f,0.f), a1 = a0;
    const float* h0p = &h[(r0 + rq    ) * D];
    const float* h1p = &h[(r0 + rq + 8) * D];
    #pragma unroll 4
    for (int kq = 0; kq < D; kq += 4) {
        float4 w0 = *(const float4*)&Wt[(kq + 0) * 132 + c4];
        float4 w1 = *(const float4*)&Wt[(kq + 1) * 132 + c4];
        float4 w2 = *(const float4*)&Wt[(kq + 2) * 132 + c4];
        float4 w3 = *(const float4*)&Wt[(kq + 3) * 132 + c4];
        float4 hv;
        hv = *(const float4*)&h0p[kq];   // wave-broadcast 16B
        FMA4(a0, hv.x, w0); FMA4(a0, hv.y, w1); FMA4(a0, hv.z, w2); FMA4(a0, hv.w, w3);
        hv = *(const float4*)&h1p[kq];
        FMA4(a1, hv.x, w0); FMA4(a1, hv.y, w1); FMA4(a1, hv.z, w2); FMA4(a1, hv.w, w3);
    }
    *(ushort4*)&hwb[(r0 + rq    ) * D + c4] = make_ushort4(f2bf(a0.x), f2bf(a0.y), f2bf(a0.z), f2bf(a0.w));
    *(ushort4*)&hwb[(r0 + rq + 8) * D + c4] = make_ushort4(f2bf(a1.x), f2bf(a1.y), f2bf(a1.z), f2bf(a1.w));

    // fused s1/s2 (fp32, 32-lane group reduce), 2 rows
    float q1a = a0.x * atts[c4] + a0.y * atts[c4 + 1] + a0.z * atts[c4 + 2] + a0.w * atts[c4 + 3];
    float q2a = a0.x * atts[D + c4] + a0.y * atts[D + c4 + 1] + a0.z * atts[D + c4 + 2] + a0.w * atts[D + c4 + 3];
    float q1b = a1.x * atts[c4] + a1.y * atts[c4 + 1] + a1.z * atts[c4 + 2] + a1.w * atts[c4 + 3];
    float q2b = a1.x * atts[D + c4] + a1.y * atts[D + c4 + 1] + a1.z * atts[D + c4 + 2] + a1.w * atts[D + c4 + 3];
    #pragma unroll
    for (int m = 16; m; m >>= 1) {
        q1a += __shfl_xor(q1a, m);
        q2a += __shfl_xor(q2a, m);
        q1b += __shfl_xor(q1b, m);
        q2b += __shfl_xor(q2b, m);
    }
    if ((t & 31) == 0) {
        s1[r0 + rq    ] = q1a;
        s2[r0 + rq    ] = q2a;
        s1[r0 + rq + 8] = q1b;
        s2[r0 + rq + 8] = q2b;
    }

    // colsum partial: 2-row sums -> LDS (b128, conflict-free) -> Pb[b][col]
    *(float4*)&scr[rq * D + c4] = make_float4(a0.x + a1.x, a0.y + a1.y,
                                              a0.z + a1.z, a0.w + a1.w);
    __syncthreads();
    if (t < D) {
        float s = 0.f;
        #pragma unroll
        for (int r = 0; r < 8; ++r) s += scr[r * D + t];
        Pb[b * D + t] = s;
    }
}

// ---------------- K2: scatter (b<1024, 1 edge/thr) | S-reduce (b>=1024) -----
__global__ __launch_bounds__(256) void k_scatter(const int* __restrict__ ei,
                                                 const float* __restrict__ s1,
                                                 const float* __restrict__ s2,
                                                 int* __restrict__ cnt,
                                                 int* __restrict__ bucket,
                                                 const float* __restrict__ Pb,
                                                 float* __restrict__ S) {
    int b = blockIdx.x, t = threadIdx.x;
    if (b < 1024) {
        int g = b * 256 + t;               // one edge/thread: single atomic
        int src = ei[g];
        int dst = ei[E + g];
        float a = s1[src] + s2[dst];
        a = a > 0.f ? a : NEG_SLOPE * a;
        float w = expf(a) - 1.f;
        int pos = atomicAdd(&cnt[src * CSTRIDE], 1);   // private 64B line per row
        if (pos < CAP)
            bucket[src * CAP + pos] = (dst << 16) | (int)f2bf(w);  // 4B packed
    } else {
        // 4 reduce blocks, 32 cols each; 8-way row split, coalesced 128B reads
        __shared__ float red[256];
        int bb = b - 1024;                 // 0..3
        int c = bb * 32 + (t & 31);        // column
        int rg = t >> 5;                   // 0..7
        float s = 0.f;
        #pragma unroll 4
        for (int r = rg; r < HWB; r += 8)
            s += Pb[r * D + c];
        red[t] = s;
        __syncthreads();
        if (t < 32) {
            float v = red[t] + red[t + 32] + red[t + 64] + red[t + 96]
                    + red[t + 128] + red[t + 160] + red[t + 192] + red[t + 224];
            S[bb * 32 + t] = v;
        }
    }
}

// ---------------- K3: per-row gather, 8 entries/iter, bitmap-prepass dedup ---
// 2048 blocks x 256 thr, 1 row/wave. LDS-staged bucket, b128 broadcasts.
// Dedup done ONCE up front: wave-private 8192-bit LDS bitmap, atomicOr claim,
// losers zero their packed w in LDS. Main loop is ballot-free.
__global__ __launch_bounds__(256) void k_row(const int* __restrict__ bucket,
                                             const int* __restrict__ cnt,
                                             const unsigned short* __restrict__ hwb,
                                             const float* __restrict__ S,
                                             float* __restrict__ out) {
    __shared__ int lb[4][CAP];             // 1.5KB, 16B-aligned per wave
    __shared__ unsigned bm[4][256];        // 8192-bit dedup bitmap per wave (4KB)
    int t = threadIdx.x;
    int wv = t >> 6, lane = t & 63;
    int row = blockIdx.x * 4 + wv;
    int deg = cnt[row * CSTRIDE];
    if (deg > CAP) deg = CAP;
    // zero wave-private bitmap: 64 lanes x 16B, conflict-free
    *(uint4*)&bm[wv][lane * 4] = make_uint4(0u, 0u, 0u, 0u);
    const int* bk = bucket + row * CAP;
    int e0 = bk[lane];
    int e1 = (lane < CAP - 64) ? bk[64 + lane] : 0;
    int p0 = (lane < deg)      ? e0 : 0;   // dead slots: w=0
    int p1 = (64 + lane < deg) ? e1 : 0;
    // dedup pre-pass: exactly one claimant per dst survives (dup w bit-identical)
    if (lane < deg) {
        unsigned d = (unsigned)p0 >> 16;
        unsigned m = 1u << (d & 31);
        if (atomicOr(&bm[wv][d >> 5], m) & m) p0 &= ~0xFFFF;   // loser: w=0
    }
    if (64 + lane < deg) {
        unsigned d = (unsigned)p1 >> 16;
        unsigned m = 1u << (d & 31);
        if (atomicOr(&bm[wv][d >> 5], m) & m) p1 &= ~0xFFFF;
    }
    lb[wv][lane] = p0;
    if (lane < CAP - 64) lb[wv][64 + lane] = p1;
    int n0 = deg < 64 ? deg : 64;
    float accx = 0.f, accy = 0.f, dex = 0.f;
    const int* myb = lb[wv];
    int col2 = lane * 2;
    int j = 0;
    for (; j + 8 <= n0; j += 8) {
        int4 pa = *(const int4*)&myb[j];        // 2x ds_read_b128 broadcast
        int4 pb = *(const int4*)&myb[j + 4];
        int da0 = pa.x >> 16, da1 = pa.y >> 16, da2 = pa.z >> 16, da3 = pa.w >> 16;
        int db0 = pb.x >> 16, db1 = pb.y >> 16, db2 = pb.z >> 16, db3 = pb.w >> 16;
        unsigned ha0 = *(const unsigned*)&hwb[da0 * D + col2];   // 8 in flight
        unsigned ha1 = *(const unsigned*)&hwb[da1 * D + col2];
        unsigned ha2 = *(const unsigned*)&hwb[da2 * D + col2];
        unsigned ha3 = *(const unsigned*)&hwb[da3 * D + col2];
        unsigned hb0 = *(const unsigned*)&hwb[db0 * D + col2];
        unsigned hb1 = *(const unsigned*)&hwb[db1 * D + col2];
        unsigned hb2 = *(const unsigned*)&hwb[db2 * D + col2];
        unsigned hb3 = *(const unsigned*)&hwb[db3 * D + col2];
        float wa0 = bf2f_low(pa.x);
        float wa1 = bf2f_low(pa.y);
        float wa2 = bf2f_low(pa.z);
        float wa3 = bf2f_low(pa.w);
        float wb0 = bf2f_low(pb.x);
        float wb1 = bf2f_low(pb.y);
        float wb2 = bf2f_low(pb.z);
        float wb3 = bf2f_low(pb.w);
        accx += wa0 * __uint_as_float(ha0 << 16);
        accy += wa0 * __uint_as_float(ha0 & 0xFFFF0000u);
        accx += wa1 * __uint_as_float(ha1 << 16);
        accy += wa1 * __uint_as_float(ha1 & 0xFFFF0000u);
        accx += wa2 * __uint_as_float(ha2 << 16);
        accy += wa2 * __uint_as_float(ha2 & 0xFFFF0000u);
        accx += wa3 * __uint_as_float(ha3 << 16);
        accy += wa3 * __uint_as_float(ha3 & 0xFFFF0000u);
        accx += wb0 * __uint_as_float(hb0 << 16);
        accy += wb0 * __uint_as_float(hb0 & 0xFFFF0000u);
        accx += wb1 * __uint_as_float(hb1 << 16);
        accy += wb1 * __uint_as_float(hb1 & 0xFFFF0000u);
        accx += wb2 * __uint_as_float(hb2 << 16);
        accy += wb2 * __uint_as_float(hb2 & 0xFFFF0000u);
        accx += wb3 * __uint_as_float(hb3 << 16);
        accy += wb3 * __uint_as_float(hb3 & 0xFFFF0000u);
        dex += wa0 + wa1 + wa2 + wa3 + wb0 + wb1 + wb2 + wb3;
    }
    for (; j < n0; ++j) {                   // tail (<8 entries)
        int pj = myb[j];
        int dj = pj >> 16;
        float wj = bf2f_low(pj);
        unsigned hv = *(const unsigned*)&hwb[dj * D + col2];
        accx += wj * __uint_as_float(hv << 16);
        accy += wj * __uint_as_float(hv & 0xFFFF0000u);
        dex += wj;
    }
    for (j = 64; j < deg; ++j) {            // slots 64..95 (rare: deg>64)
        int pj = myb[j];
        int dj = pj >> 16;
        float wj = bf2f_low(pj);
        unsigned hv = *(const unsigned*)&hwb[dj * D + col2];
        accx += wj * __uint_as_float(hv << 16);
        accy += wj * __uint_as_float(hv & 0xFFFF0000u);
        dex += wj;
    }
    float inv = 1.f / ((float)V + dex);
    float2 s = *(const float2*)&S[col2];
    float2 o;
    o.x = (s.x + accx) * inv;
    o.y = (s.y + accy) * inv;
    *(float2*)&out[row * D + col2] = o;
}

extern "C" void kernel_launch(void* const* d_in, const int* in_sizes, int n_in,
                              void* d_out, int out_size, void* d_ws, size_t ws_size,
                              hipStream_t stream) {
    const float* h   = (const float*)d_in[0];
    const int*   ei  = (const int*)d_in[1];
    const float* W   = (const float*)d_in[2];
    const float* att = (const float*)d_in[3];
    float* out = (float*)d_out;

    char* ws = (char*)d_ws;
    // workspace layout (bytes):
    //   hwb    @ 0          2,097,152   (bf16 hw)
    //   s1     @ 2,097,152     32,768
    //   s2     @ 2,129,920     32,768
    //   S      @ 2,162,688        512
    //   cnt    @ 2,163,200    524,288   (V counters padded to 64B lines)
    //   bucket @ 2,687,488  3,145,728   (8192 * 96 * 4B packed)
    //   Pb     @ 5,833,216    262,144   (512 blocks * 128 colsum partials)
    unsigned short* hwb = (unsigned short*)(ws);
    float* s1  = (float*)(ws + 2097152);
    float* s2  = (float*)(ws + 2129920);
    float* S   = (float*)(ws + 2162688);
    int*   cnt = (int*)(ws + 2163200);
    int*   bucket = (int*)(ws + 2687488);
    float* Pb  = (float*)(ws + 5833216);

    k_hw     <<<HWB,  256, 0, stream>>>(h, W, att, hwb, s1, s2, Pb, cnt);
    k_scatter<<<1028, 256, 0, stream>>>(ei, s1, s2, cnt, bucket, Pb, S);
    k_row    <<<2048, 256, 0, stream>>>(bucket, cnt, hwb, S, out);
}